// Round 8
// baseline (220.322 us; speedup 1.0000x reference)
//
#include <hip/hip_runtime.h>
#include <hip/hip_bf16.h>
#include <math.h>
#include <stdint.h>

#define BB 4
#define TT 1024
#define EE 1024
#define HH 16
#define SS 64

typedef unsigned short ushort_t;
typedef __attribute__((ext_vector_type(8))) short bf16x8;
typedef __attribute__((ext_vector_type(8))) unsigned short u16x8;
typedef __attribute__((ext_vector_type(4))) unsigned short u16x4;
typedef __attribute__((ext_vector_type(4))) float f32x4;

__device__ __forceinline__ float b2f(ushort_t u) {
    union { float f; uint32_t i; } c;
    c.i = ((uint32_t)u) << 16;
    return c.f;
}
__device__ __forceinline__ ushort_t f2b(float f) {
    __hip_bfloat16 h = __float2bfloat16(f);
    return *(ushort_t*)&h;
}

// ---------------------------------------------------------------------------
// Kernel 0: fused fp32 -> bf16 converter (Er, Wo, and Wq|Wk|Wv) + vmean zero.
// ---------------------------------------------------------------------------
__global__ __launch_bounds__(256) void cvt2_kernel(
    const float* __restrict__ a, ushort_t* __restrict__ da, int na,
    const float* __restrict__ b, ushort_t* __restrict__ db, int nb,
    const float* __restrict__ w0, const float* __restrict__ w1,
    const float* __restrict__ w2, ushort_t* __restrict__ dw,
    float* __restrict__ vmean)
{
    if (blockIdx.x == 0) {
        const float4 zz = {0.f, 0.f, 0.f, 0.f};
#pragma unroll
        for (int z = 0; z < 4; z++)
            ((float4*)vmean)[threadIdx.x * 4 + z] = zz;   // 4096 floats
    }
    const int i4 = (blockIdx.x * 256 + threadIdx.x) * 4;
    if (i4 < na) {
        const float4 xv = *(const float4*)&a[i4];
        u16x4 o4 = { f2b(xv.x), f2b(xv.y), f2b(xv.z), f2b(xv.w) };
        *(u16x4*)&da[i4] = o4;
    } else {
        const int j4 = i4 - na;
        if (j4 < nb) {
            const float4 xv = *(const float4*)&b[j4];
            u16x4 o4 = { f2b(xv.x), f2b(xv.y), f2b(xv.z), f2b(xv.w) };
            *(u16x4*)&db[j4] = o4;
        } else {
            const int k4 = j4 - nb;                       // [0, 12288)
            if (k4 < 3 * 4096) {
                const float* src = (k4 < 4096) ? w0 : (k4 < 8192) ? w1 : w2;
                const int off = k4 & 4095;
                const float4 xv = *(const float4*)&src[off];
                u16x4 o4 = { f2b(xv.x), f2b(xv.y), f2b(xv.z), f2b(xv.w) };
                *(u16x4*)&dw[k4] = o4;                    // layout [mo][64][64]
            }
        }
    }
}

// ---------------------------------------------------------------------------
// Kernel 1: MFMA q/k/v projection + fused vmean accumulation.
// R7: (a) W staged as pre-converted bf16 (6 uint4 copies/thread, no f2b);
//     (b) epilogue vectorized: acc -> LDS (reusing Xs, identical (t,d)
//         mapping) -> 4 uint4 global stores per mo (was 32 scalar ushort).
// MFMA core and vmean logic are R0-verbatim.
// ---------------------------------------------------------------------------
__global__ __launch_bounds__(256) void qkv_kernel(
    const float* __restrict__ x, const ushort_t* __restrict__ w16,
    ushort_t* __restrict__ q, ushort_t* __restrict__ k, ushort_t* __restrict__ v,
    float* __restrict__ vmean)
{
    __shared__ __align__(16) ushort_t Xs[128][72];
    __shared__ __align__(16) ushort_t Wl[3][64][72];

    const int tid  = threadIdx.x;
    const int lane = tid & 63;
    const int w    = tid >> 6;
    const int m    = lane & 15;
    const int qd   = lane >> 4;
    const int n0   = blockIdx.x * 128;
    const int hh   = blockIdx.y;
    const int bb   = n0 >> 10;

#pragma unroll
    for (int l = 0; l < 8; l++) {
        const int idx = tid + 256 * l;
        const int row = idx >> 4;
        const int c4  = idx & 15;
        const float4 xv = *(const float4*)&x[(size_t)(n0 + row) * 1024 + hh * 64 + c4 * 4];
        u16x4 o4 = { f2b(xv.x), f2b(xv.y), f2b(xv.z), f2b(xv.w) };
        *(u16x4*)&Xs[row][c4 * 4] = o4;
    }
    // W staging: 1536 uint4 of bf16 weights, linear -> [mo][r][sub*8]
#pragma unroll
    for (int l = 0; l < 6; l++) {
        const int idx = tid + 256 * l;          // = mo*512 + r*8 + sub
        const int mo  = idx >> 9;
        const int rem = idx & 511;
        const int r   = rem >> 3;
        const int sub = rem & 7;
        *(uint4*)&Wl[mo][r][sub * 8] = ((const uint4*)w16)[idx];
    }
    __syncthreads();

    f32x4 acc[2][3][4];
#pragma unroll
    for (int rt = 0; rt < 2; rt++)
#pragma unroll
        for (int mo = 0; mo < 3; mo++)
#pragma unroll
            for (int ct = 0; ct < 4; ct++) acc[rt][mo][ct] = {0.f, 0.f, 0.f, 0.f};

#pragma unroll
    for (int ks = 0; ks < 2; ks++) {
        bf16x8 af[2];
#pragma unroll
        for (int rt = 0; rt < 2; rt++)
            af[rt] = *(const bf16x8*)&Xs[32 * w + 16 * rt + m][ks * 32 + qd * 8];
#pragma unroll
        for (int mo = 0; mo < 3; mo++)
#pragma unroll
            for (int ct = 0; ct < 4; ct++) {
                bf16x8 bw = *(const bf16x8*)&Wl[mo][ct * 16 + m][ks * 32 + qd * 8];
#pragma unroll
                for (int rt = 0; rt < 2; rt++)
                    acc[rt][mo][ct] = __builtin_amdgcn_mfma_f32_16x16x32_bf16(
                        af[rt], bw, acc[rt][mo][ct], 0, 0, 0);
            }
    }

    // ---- vectorized epilogue: acc -> Xs (as [128][72]) -> uint4 stores ----
    const size_t obase = ((size_t)bb * HH + hh) * TT;
    const int t0 = n0 & 1023;
    __syncthreads();                       // all waves done reading Xs/Wl
#pragma unroll
    for (int mo = 0; mo < 3; mo++) {
        ushort_t* dst = (mo == 0) ? q : (mo == 1) ? k : v;
        const float sc = (mo == 1) ? 0.03125f : 1.0f;
#pragma unroll
        for (int rt = 0; rt < 2; rt++)
#pragma unroll
            for (int reg = 0; reg < 4; reg++) {
                const int trow = 32 * w + 16 * rt + qd * 4 + reg;
#pragma unroll
                for (int ct = 0; ct < 4; ct++)
                    Xs[trow][ct * 16 + m] = f2b(acc[rt][mo][ct][reg] * sc);
            }
        __syncthreads();
#pragma unroll
        for (int l = 0; l < 4; l++) {
            const int idx = tid + 256 * l;
            const int row = idx >> 3;
            const int sub = idx & 7;
            ((uint4*)dst)[(obase + t0 + row) * 8 + sub] = *(const uint4*)&Xs[row][sub * 8];
        }
        __syncthreads();
    }

#pragma unroll
    for (int ct = 0; ct < 4; ct++) {
        float s = 0.f;
#pragma unroll
        for (int rt = 0; rt < 2; rt++)
#pragma unroll
            for (int reg = 0; reg < 4; reg++) s += acc[rt][2][ct][reg];
        s += __shfl_xor(s, 16);
        s += __shfl_xor(s, 32);
        if (qd == 0)
            atomicAdd(&vmean[(bb * HH + hh) * SS + ct * 16 + m], s);
    }
}

// ---------------------------------------------------------------------------
// Kernel 3: MFMA bf16 flash attention (verified R0 structure, 58.8us).
// ---------------------------------------------------------------------------
__global__ __launch_bounds__(256) void attn_kernel(
    const ushort_t* __restrict__ q, const ushort_t* __restrict__ k,
    const ushort_t* __restrict__ v, const ushort_t* __restrict__ er,
    const int* __restrict__ mask, const float* __restrict__ vmean,
    ushort_t* __restrict__ attn)
{
    __shared__ __align__(16) ushort_t Qs[64][72];
    __shared__ __align__(16) ushort_t Ks[32][72];
    __shared__ __align__(16) ushort_t Vt4[4][64][8];
    __shared__ __align__(16) ushort_t Es[96][72];
    __shared__ __align__(16) ushort_t Ps[4][16][40];

    const int tid  = threadIdx.x;
    const int lane = tid & 63;
    const int w    = tid >> 6;
    const int m    = lane & 15;
    const int qd   = lane >> 4;
    const int bh   = blockIdx.x;
    const int bb   = bh >> 4;
    const int hh   = bh & 15;
    const int i0   = blockIdx.y * 64;

    const ushort_t* qb = q + (size_t)bh * TT * SS;
    const ushort_t* kb = k + (size_t)bh * TT * SS;
    const ushort_t* vb = v + (size_t)bh * TT * SS;
    const ushort_t* eb = er + (size_t)hh * TT * SS;
    const int l0 = 960 - i0;

    for (int c = tid; c < 512; c += 256) {
        int row = c >> 3, sub = c & 7;
        *(uint4*)&Qs[row][sub * 8] = ((const uint4*)qb)[(size_t)(i0 + row) * 8 + sub];
    }
    for (int c = tid; c < 512; c += 256) {
        int row = c >> 3, sub = c & 7;
        int l = l0 + row;
        uint4 val = {0u, 0u, 0u, 0u};
        if (l <= 1023) val = ((const uint4*)eb)[(size_t)l * 8 + sub];
        *(uint4*)&Es[row][sub * 8] = val;
    }

    const int krow = tid >> 3, ksub = tid & 7;
    const int vd   = tid & 63, vjh = tid >> 6;
    uint4 kreg, ereg;
    u16x8 vreg;

    {
        kreg = ((const uint4*)kb)[(size_t)krow * 8 + ksub];
#pragma unroll
        for (int jj = 0; jj < 8; jj++)
            vreg[jj] = vb[(size_t)(vjh * 8 + jj) * SS + vd];
        const int l = l0 + 64 + krow;
        ereg = (uint4){0u, 0u, 0u, 0u};
        if (l <= 1023) ereg = ((const uint4*)eb)[(size_t)l * 8 + ksub];
    }
    __syncthreads();

    bf16x8 aq[2];
#pragma unroll
    for (int ks = 0; ks < 2; ks++)
        aq[ks] = *(const bf16x8*)&Qs[16 * w + m][ks * 32 + qd * 8];

    f32x4 o[4];
#pragma unroll
    for (int vt = 0; vt < 4; vt++) o[vt] = {0.f, 0.f, 0.f, 0.f};
    float lsum[4] = {0.f, 0.f, 0.f, 0.f};

    const int ow = 48 - 16 * w;
    const int srcbase = lane & 48;

    for (int j0 = 0; j0 <= i0 + 32; j0 += 32) {
        *(uint4*)&Ks[krow][ksub * 8] = kreg;
        *(u16x8*)&Vt4[vjh][vd][0] = vreg;
        {
            const int slot = (64 + j0) % 96 + krow;
            *(uint4*)&Es[slot][ksub * 8] = ereg;
        }
        __syncthreads();

        if (j0 <= i0) {
            const int jn = j0 + 32;
            kreg = ((const uint4*)kb)[(size_t)(jn + krow) * 8 + ksub];
#pragma unroll
            for (int jj = 0; jj < 8; jj++)
                vreg[jj] = vb[(size_t)(jn + vjh * 8 + jj) * SS + vd];
            const int l = l0 + 64 + jn + krow;
            ereg = (uint4){0u, 0u, 0u, 0u};
            if (l <= 1023) ereg = ((const uint4*)eb)[(size_t)l * 8 + ksub];
        }

        f32x4 s[2];
#pragma unroll
        for (int ct = 0; ct < 2; ct++) {
            s[ct] = {0.f, 0.f, 0.f, 0.f};
#pragma unroll
            for (int ks = 0; ks < 2; ks++) {
                bf16x8 bk = *(const bf16x8*)&Ks[16 * ct + m][ks * 32 + qd * 8];
                s[ct] = __builtin_amdgcn_mfma_f32_16x16x32_bf16(aq[ks], bk, s[ct], 0, 0, 0);
            }
        }
        f32x4 r[3];
#pragma unroll
        for (int rt = 0; rt < 3; rt++) {
            const int row0 = (ow + 16 * rt + j0) % 96;
            r[rt] = {0.f, 0.f, 0.f, 0.f};
#pragma unroll
            for (int ks = 0; ks < 2; ks++) {
                bf16x8 be = *(const bf16x8*)&Es[row0 + m][ks * 32 + qd * 8];
                r[rt] = __builtin_amdgcn_mfma_f32_16x16x32_bf16(aq[ks], be, r[rt], 0, 0, 0);
            }
        }

#pragma unroll
        for (int reg = 0; reg < 4; reg++) {
            const int r_ = qd * 4 + reg;
            const int i_ = i0 + 16 * w + r_;
            const int base = 15 - r_ + m;
            const int src  = srcbase | (base & 15);
            const float c0 = __shfl(r[0][reg], src);
            const float c1 = __shfl(r[1][reg], src);
            const float c2 = __shfl(r[2][reg], src);
            const float e0 = (base < 16) ? c0 : c1;
            const float e1 = (base < 16) ? c1 : c2;
            const float v0 = s[0][reg] + e0;
            const float v1 = s[1][reg] + e1;
            const float p0 = (j0 + m      > i_) ? 0.f : __expf(v0);
            const float p1 = (j0 + m + 16 > i_) ? 0.f : __expf(v1);
            lsum[reg] += p0 + p1;
            Ps[w][r_][m]      = f2b(p0);
            Ps[w][r_][m + 16] = f2b(p1);
        }

        bf16x8 pa = *(const bf16x8*)&Ps[w][m][qd * 8];
#pragma unroll
        for (int vt = 0; vt < 4; vt++) {
            bf16x8 bv = *(const bf16x8*)&Vt4[qd][16 * vt + m][0];
            o[vt] = __builtin_amdgcn_mfma_f32_16x16x32_bf16(pa, bv, o[vt], 0, 0, 0);
        }
        __syncthreads();
    }

#pragma unroll
    for (int reg = 0; reg < 4; reg++) {
        float l = lsum[reg];
#pragma unroll
        for (int off = 1; off < 16; off <<= 1) l += __shfl_xor(l, off);
        const int r_ = qd * 4 + reg;
        const int i_ = i0 + 16 * w + r_;
        const bool pad = (mask[bb * TT + i_] == 0);
        const float inv = 1.0f / l;
        const size_t rowbase = ((size_t)bb * TT + hh * 64 + (i_ >> 4)) * EE + (i_ & 15) * 64;
#pragma unroll
        for (int vt = 0; vt < 4; vt++) {
            const int d_ = 16 * vt + m;
            float val = pad ? vmean[bh * SS + d_] * (1.0f / 1024.0f)
                            : o[vt][reg] * inv;
            attn[rowbase + d_] = f2b(val);
        }
    }
}

// ---------------------------------------------------------------------------
// Kernel 4: MFMA bf16 GEMM  out = M @ Wo16^T + bo.
// R7: BM=64, BN=64 -> 1024 blocks (4/CU).  XCD-pinned swizzle: assuming
// linear-id round-robin across 8 XCDs, XCD k owns n-tiles 8k..8k+7 for all
// 16 o-tiles -> per-XCD L2 footprint = 1MB A + 2MB B (fits 4MB) so A is
// fetched from HBM once instead of 16x.  Register prefetch double-buffer
// kept.  Index algebra (A rows / Wo rows / out) unchanged from verified.
// ---------------------------------------------------------------------------
__global__ __launch_bounds__(256) void outproj_kernel(
    const ushort_t* __restrict__ A, const ushort_t* __restrict__ Wo,
    const float* __restrict__ bo, float* __restrict__ out)
{
    __shared__ __align__(16) ushort_t As[64][72];
    __shared__ __align__(16) ushort_t Bs[64][72];

    const int tid  = threadIdx.x;
    const int lane = tid & 63;
    const int w    = tid >> 6;
    const int m    = lane & 15;
    const int qd   = lane >> 4;

    const int lin  = blockIdx.x;           // 0..1023
    const int xcd  = lin & 7;
    const int slot = lin >> 3;             // 0..127
    const int n0   = (xcd * 8 + (slot & 7)) * 64;
    const int o0   = (slot >> 3) * 64;

    const int srow = tid >> 3;             // 0..31
    const int ssub = tid & 7;

    uint4 pa[2], pb[2];
#pragma unroll
    for (int l = 0; l < 2; l++) {
        pa[l] = *(const uint4*)&A[(size_t)(n0 + srow + 32 * l) * 1024 + ssub * 8];
        pb[l] = *(const uint4*)&Wo[(size_t)(o0 + srow + 32 * l) * 1024 + ssub * 8];
    }

    f32x4 acc[4];
#pragma unroll
    for (int ct = 0; ct < 4; ct++) acc[ct] = {0.f, 0.f, 0.f, 0.f};

    for (int k0 = 0; k0 < 1024; k0 += 64) {
        __syncthreads();
#pragma unroll
        for (int l = 0; l < 2; l++) {
            *(uint4*)&As[srow + 32 * l][ssub * 8] = pa[l];
            *(uint4*)&Bs[srow + 32 * l][ssub * 8] = pb[l];
        }
        __syncthreads();

        if (k0 + 64 < 1024) {
            const int kn = k0 + 64;
#pragma unroll
            for (int l = 0; l < 2; l++) {
                pa[l] = *(const uint4*)&A[(size_t)(n0 + srow + 32 * l) * 1024 + kn + ssub * 8];
                pb[l] = *(const uint4*)&Wo[(size_t)(o0 + srow + 32 * l) * 1024 + kn + ssub * 8];
            }
        }

#pragma unroll
        for (int ks = 0; ks < 2; ks++) {
            bf16x8 af = *(const bf16x8*)&As[16 * w + m][ks * 32 + qd * 8];
#pragma unroll
            for (int ct = 0; ct < 4; ct++) {
                bf16x8 bf = *(const bf16x8*)&Bs[ct * 16 + m][ks * 32 + qd * 8];
                acc[ct] = __builtin_amdgcn_mfma_f32_16x16x32_bf16(af, bf, acc[ct], 0, 0, 0);
            }
        }
    }

#pragma unroll
    for (int ct = 0; ct < 4; ct++) {
        const int oc = o0 + ct * 16 + m;
        const float bias = bo[oc];
#pragma unroll
        for (int reg = 0; reg < 4; reg++) {
            const int n = n0 + 16 * w + qd * 4 + reg;
            out[(size_t)n * EE + oc] = acc[ct][reg] + bias;
        }
    }
}

// ---------------------------------------------------------------------------
// Launcher.  ws (ushort): q16|k16|v16 (4M each) | er16 (1M) | wo16 (1M)
//            | w316 (12288) | M16 (4M) | vmean f32 (4096)
// ---------------------------------------------------------------------------
extern "C" void kernel_launch(void* const* d_in, const int* in_sizes, int n_in,
                              void* d_out, int out_size, void* d_ws, size_t ws_size,
                              hipStream_t stream)
{
    const float* x    = (const float*)d_in[0];
    const int*   mask = (const int*)d_in[1];
    const float* Wq   = (const float*)d_in[2];
    const float* Wk   = (const float*)d_in[3];
    const float* Wv   = (const float*)d_in[4];
    const float* Er   = (const float*)d_in[5];
    const float* Wo   = (const float*)d_in[6];
    const float* bo   = (const float*)d_in[7];
    float* out = (float*)d_out;

    const size_t QKV = (size_t)BB * HH * TT * SS;
    const int    nEr = HH * TT * SS;
    const int    nWo = EE * EE;
    const int    nW3 = 3 * SS * SS;
    ushort_t* q16   = (ushort_t*)d_ws;
    ushort_t* k16   = q16 + QKV;
    ushort_t* v16   = k16 + QKV;
    ushort_t* er16  = v16 + QKV;
    ushort_t* wo16  = er16 + nEr;
    ushort_t* w316  = wo16 + nWo;
    ushort_t* M16   = w316 + nW3;
    float*    vmean = (float*)(M16 + QKV);

    cvt2_kernel<<<dim3((nEr + nWo + nW3) / 1024), 256, 0, stream>>>(
        Er, er16, nEr, Wo, wo16, nWo, Wq, Wk, Wv, w316, vmean);
    qkv_kernel<<<dim3(BB * TT / 128, HH), 256, 0, stream>>>(x, w316, q16, k16, v16, vmean);
    attn_kernel<<<dim3(BB * HH, TT / 64), 256, 0, stream>>>(q16, k16, v16, er16, mask, vmean, M16);
    outproj_kernel<<<dim3(EE / 64 * (BB * TT / 64)), 256, 0, stream>>>(M16, wo16, bo, out);
}

// Round 9
// 198.341 us; speedup vs baseline: 1.1108x; 1.1108x over previous
//
#include <hip/hip_runtime.h>
#include <hip/hip_bf16.h>
#include <math.h>
#include <stdint.h>

#define BB 4
#define TT 1024
#define EE 1024
#define HH 16
#define SS 64

typedef unsigned short ushort_t;
typedef __attribute__((ext_vector_type(8))) short bf16x8;
typedef __attribute__((ext_vector_type(8))) unsigned short u16x8;
typedef __attribute__((ext_vector_type(4))) unsigned short u16x4;
typedef __attribute__((ext_vector_type(4))) float f32x4;

__device__ __forceinline__ float b2f(ushort_t u) {
    union { float f; uint32_t i; } c;
    c.i = ((uint32_t)u) << 16;
    return c.f;
}
__device__ __forceinline__ ushort_t f2b(float f) {
    __hip_bfloat16 h = __float2bfloat16(f);
    return *(ushort_t*)&h;
}

// ---------------------------------------------------------------------------
// Kernel 1 (merged): blocks [0,2048) convert Er|Wo fp32->bf16 (cvt2 path);
// blocks [2048,2560) run the R0-verbatim MFMA q/k/v projection + vmean.
// One launch instead of two (saves an inter-launch gap); the qkv part uses
// fp32 W loads exactly as the verified R0 kernel did.
// ---------------------------------------------------------------------------
__global__ __launch_bounds__(256) void prep_kernel(
    const float* __restrict__ Er, ushort_t* __restrict__ er16,
    const float* __restrict__ Wo, ushort_t* __restrict__ wo16,
    const float* __restrict__ x, const float* __restrict__ Wq,
    const float* __restrict__ Wk, const float* __restrict__ Wv,
    ushort_t* __restrict__ q, ushort_t* __restrict__ k, ushort_t* __restrict__ v,
    float* __restrict__ vmean)
{
    __shared__ __align__(16) ushort_t Xs[128][72];
    __shared__ __align__(16) ushort_t Wl[3][64][72];

    const int bid = blockIdx.x;
    const int tid = threadIdx.x;

    if (bid < 2048) {
        // ---- cvt path: nEr = nWo = 1048576; grid covers exactly both ----
        const int nEr = HH * TT * SS;
        const int i4 = (bid * 256 + tid) * 4;
        if (i4 < nEr) {
            const float4 xv = *(const float4*)&Er[i4];
            u16x4 o4 = { f2b(xv.x), f2b(xv.y), f2b(xv.z), f2b(xv.w) };
            *(u16x4*)&er16[i4] = o4;
        } else {
            const int j4 = i4 - nEr;
            const float4 xv = *(const float4*)&Wo[j4];
            u16x4 o4 = { f2b(xv.x), f2b(xv.y), f2b(xv.z), f2b(xv.w) };
            *(u16x4*)&wo16[j4] = o4;
        }
        return;
    }

    // ---- qkv path (R0-verbatim body) ----
    const int bid2 = bid - 2048;            // 0..511
    const int lane = tid & 63;
    const int w    = tid >> 6;
    const int m    = lane & 15;
    const int qd   = lane >> 4;
    const int n0   = (bid2 & 31) * 128;
    const int hh   = bid2 >> 5;
    const int bb   = n0 >> 10;

#pragma unroll
    for (int l = 0; l < 8; l++) {
        const int idx = tid + 256 * l;
        const int row = idx >> 4;
        const int c4  = idx & 15;
        const float4 xv = *(const float4*)&x[(size_t)(n0 + row) * 1024 + hh * 64 + c4 * 4];
        u16x4 o4 = { f2b(xv.x), f2b(xv.y), f2b(xv.z), f2b(xv.w) };
        *(u16x4*)&Xs[row][c4 * 4] = o4;
    }
#pragma unroll
    for (int l = 0; l < 12; l++) {
        const int idx = tid + 256 * l;
        const int mo  = idx >> 10;
        const int r   = (idx >> 4) & 63;
        const int c4  = idx & 15;
        const float* W = (mo == 0) ? Wq : (mo == 1) ? Wk : Wv;
        const float4 wv = *(const float4*)&W[r * 64 + c4 * 4];
        u16x4 o4 = { f2b(wv.x), f2b(wv.y), f2b(wv.z), f2b(wv.w) };
        *(u16x4*)&Wl[mo][r][c4 * 4] = o4;
    }
    __syncthreads();

    f32x4 acc[2][3][4];
#pragma unroll
    for (int rt = 0; rt < 2; rt++)
#pragma unroll
        for (int mo = 0; mo < 3; mo++)
#pragma unroll
            for (int ct = 0; ct < 4; ct++) acc[rt][mo][ct] = {0.f, 0.f, 0.f, 0.f};

#pragma unroll
    for (int ks = 0; ks < 2; ks++) {
        bf16x8 af[2];
#pragma unroll
        for (int rt = 0; rt < 2; rt++)
            af[rt] = *(const bf16x8*)&Xs[32 * w + 16 * rt + m][ks * 32 + qd * 8];
#pragma unroll
        for (int mo = 0; mo < 3; mo++)
#pragma unroll
            for (int ct = 0; ct < 4; ct++) {
                bf16x8 bw = *(const bf16x8*)&Wl[mo][ct * 16 + m][ks * 32 + qd * 8];
#pragma unroll
                for (int rt = 0; rt < 2; rt++)
                    acc[rt][mo][ct] = __builtin_amdgcn_mfma_f32_16x16x32_bf16(
                        af[rt], bw, acc[rt][mo][ct], 0, 0, 0);
            }
    }

    const size_t obase = ((size_t)bb * HH + hh) * TT;
#pragma unroll
    for (int mo = 0; mo < 3; mo++) {
        ushort_t* dst = (mo == 0) ? q : (mo == 1) ? k : v;
        const float sc = (mo == 1) ? 0.03125f : 1.0f;
#pragma unroll
        for (int rt = 0; rt < 2; rt++)
#pragma unroll
            for (int reg = 0; reg < 4; reg++) {
                const int t = (n0 & 1023) + 32 * w + 16 * rt + qd * 4 + reg;
#pragma unroll
                for (int ct = 0; ct < 4; ct++)
                    dst[(obase + t) * SS + ct * 16 + m] = f2b(acc[rt][mo][ct][reg] * sc);
            }
    }

#pragma unroll
    for (int ct = 0; ct < 4; ct++) {
        float s = 0.f;
#pragma unroll
        for (int rt = 0; rt < 2; rt++)
#pragma unroll
            for (int reg = 0; reg < 4; reg++) s += acc[rt][2][ct][reg];
        s += __shfl_xor(s, 16);
        s += __shfl_xor(s, 32);
        if (qd == 0)
            atomicAdd(&vmean[(bb * HH + hh) * SS + ct * 16 + m], s);
    }
}

// ---------------------------------------------------------------------------
// Kernel 3: MFMA bf16 flash attention (verified R0 structure, 58.8us).
// ---------------------------------------------------------------------------
__global__ __launch_bounds__(256) void attn_kernel(
    const ushort_t* __restrict__ q, const ushort_t* __restrict__ k,
    const ushort_t* __restrict__ v, const ushort_t* __restrict__ er,
    const int* __restrict__ mask, const float* __restrict__ vmean,
    ushort_t* __restrict__ attn)
{
    __shared__ __align__(16) ushort_t Qs[64][72];
    __shared__ __align__(16) ushort_t Ks[32][72];
    __shared__ __align__(16) ushort_t Vt4[4][64][8];
    __shared__ __align__(16) ushort_t Es[96][72];
    __shared__ __align__(16) ushort_t Ps[4][16][40];

    const int tid  = threadIdx.x;
    const int lane = tid & 63;
    const int w    = tid >> 6;
    const int m    = lane & 15;
    const int qd   = lane >> 4;
    const int bh   = blockIdx.x;
    const int bb   = bh >> 4;
    const int hh   = bh & 15;
    const int i0   = blockIdx.y * 64;

    const ushort_t* qb = q + (size_t)bh * TT * SS;
    const ushort_t* kb = k + (size_t)bh * TT * SS;
    const ushort_t* vb = v + (size_t)bh * TT * SS;
    const ushort_t* eb = er + (size_t)hh * TT * SS;
    const int l0 = 960 - i0;

    for (int c = tid; c < 512; c += 256) {
        int row = c >> 3, sub = c & 7;
        *(uint4*)&Qs[row][sub * 8] = ((const uint4*)qb)[(size_t)(i0 + row) * 8 + sub];
    }
    for (int c = tid; c < 512; c += 256) {
        int row = c >> 3, sub = c & 7;
        int l = l0 + row;
        uint4 val = {0u, 0u, 0u, 0u};
        if (l <= 1023) val = ((const uint4*)eb)[(size_t)l * 8 + sub];
        *(uint4*)&Es[row][sub * 8] = val;
    }

    const int krow = tid >> 3, ksub = tid & 7;
    const int vd   = tid & 63, vjh = tid >> 6;
    uint4 kreg, ereg;
    u16x8 vreg;

    {
        kreg = ((const uint4*)kb)[(size_t)krow * 8 + ksub];
#pragma unroll
        for (int jj = 0; jj < 8; jj++)
            vreg[jj] = vb[(size_t)(vjh * 8 + jj) * SS + vd];
        const int l = l0 + 64 + krow;
        ereg = (uint4){0u, 0u, 0u, 0u};
        if (l <= 1023) ereg = ((const uint4*)eb)[(size_t)l * 8 + ksub];
    }
    __syncthreads();

    bf16x8 aq[2];
#pragma unroll
    for (int ks = 0; ks < 2; ks++)
        aq[ks] = *(const bf16x8*)&Qs[16 * w + m][ks * 32 + qd * 8];

    f32x4 o[4];
#pragma unroll
    for (int vt = 0; vt < 4; vt++) o[vt] = {0.f, 0.f, 0.f, 0.f};
    float lsum[4] = {0.f, 0.f, 0.f, 0.f};

    const int ow = 48 - 16 * w;
    const int srcbase = lane & 48;

    for (int j0 = 0; j0 <= i0 + 32; j0 += 32) {
        *(uint4*)&Ks[krow][ksub * 8] = kreg;
        *(u16x8*)&Vt4[vjh][vd][0] = vreg;
        {
            const int slot = (64 + j0) % 96 + krow;
            *(uint4*)&Es[slot][ksub * 8] = ereg;
        }
        __syncthreads();

        if (j0 <= i0) {
            const int jn = j0 + 32;
            kreg = ((const uint4*)kb)[(size_t)(jn + krow) * 8 + ksub];
#pragma unroll
            for (int jj = 0; jj < 8; jj++)
                vreg[jj] = vb[(size_t)(jn + vjh * 8 + jj) * SS + vd];
            const int l = l0 + 64 + jn + krow;
            ereg = (uint4){0u, 0u, 0u, 0u};
            if (l <= 1023) ereg = ((const uint4*)eb)[(size_t)l * 8 + ksub];
        }

        f32x4 s[2];
#pragma unroll
        for (int ct = 0; ct < 2; ct++) {
            s[ct] = {0.f, 0.f, 0.f, 0.f};
#pragma unroll
            for (int ks = 0; ks < 2; ks++) {
                bf16x8 bk = *(const bf16x8*)&Ks[16 * ct + m][ks * 32 + qd * 8];
                s[ct] = __builtin_amdgcn_mfma_f32_16x16x32_bf16(aq[ks], bk, s[ct], 0, 0, 0);
            }
        }
        f32x4 r[3];
#pragma unroll
        for (int rt = 0; rt < 3; rt++) {
            const int row0 = (ow + 16 * rt + j0) % 96;
            r[rt] = {0.f, 0.f, 0.f, 0.f};
#pragma unroll
            for (int ks = 0; ks < 2; ks++) {
                bf16x8 be = *(const bf16x8*)&Es[row0 + m][ks * 32 + qd * 8];
                r[rt] = __builtin_amdgcn_mfma_f32_16x16x32_bf16(aq[ks], be, r[rt], 0, 0, 0);
            }
        }

#pragma unroll
        for (int reg = 0; reg < 4; reg++) {
            const int r_ = qd * 4 + reg;
            const int i_ = i0 + 16 * w + r_;
            const int base = 15 - r_ + m;
            const int src  = srcbase | (base & 15);
            const float c0 = __shfl(r[0][reg], src);
            const float c1 = __shfl(r[1][reg], src);
            const float c2 = __shfl(r[2][reg], src);
            const float e0 = (base < 16) ? c0 : c1;
            const float e1 = (base < 16) ? c1 : c2;
            const float v0 = s[0][reg] + e0;
            const float v1 = s[1][reg] + e1;
            const float p0 = (j0 + m      > i_) ? 0.f : __expf(v0);
            const float p1 = (j0 + m + 16 > i_) ? 0.f : __expf(v1);
            lsum[reg] += p0 + p1;
            Ps[w][r_][m]      = f2b(p0);
            Ps[w][r_][m + 16] = f2b(p1);
        }

        bf16x8 pa = *(const bf16x8*)&Ps[w][m][qd * 8];
#pragma unroll
        for (int vt = 0; vt < 4; vt++) {
            bf16x8 bv = *(const bf16x8*)&Vt4[qd][16 * vt + m][0];
            o[vt] = __builtin_amdgcn_mfma_f32_16x16x32_bf16(pa, bv, o[vt], 0, 0, 0);
        }
        __syncthreads();
    }

#pragma unroll
    for (int reg = 0; reg < 4; reg++) {
        float l = lsum[reg];
#pragma unroll
        for (int off = 1; off < 16; off <<= 1) l += __shfl_xor(l, off);
        const int r_ = qd * 4 + reg;
        const int i_ = i0 + 16 * w + r_;
        const bool pad = (mask[bb * TT + i_] == 0);
        const float inv = 1.0f / l;
        const size_t rowbase = ((size_t)bb * TT + hh * 64 + (i_ >> 4)) * EE + (i_ & 15) * 64;
#pragma unroll
        for (int vt = 0; vt < 4; vt++) {
            const int d_ = 16 * vt + m;
            float val = pad ? vmean[bh * SS + d_] * (1.0f / 1024.0f)
                            : o[vt][reg] * inv;
            attn[rowbase + d_] = f2b(val);
        }
    }
}

// ---------------------------------------------------------------------------
// Kernel 4: MFMA bf16 GEMM  out = M @ Wo16^T + bo.
// R9: 128x128 tile, grid = 256 linear blocks (1/CU).  XCD-pinned: xcd owns
// 4 n-tiles x 8 o-tiles -> per-XCD L2 = 1MB A + 2MB Wo (fits 4MB), A and Wo
// each fetched from HBM ~once.  BK=64 + register prefetch (32 MFMA/wave/iter
// hides load latency).  LDS-staged fp32 epilogue: acc -> Cs[64][132] -> full
// 512B-per-row float4 stores (kills the 5.5x write amplification R8 showed).
// Fragment/C index algebra identical to the verified R0 outproj.
// ---------------------------------------------------------------------------
__global__ __launch_bounds__(256) void outproj_kernel(
    const ushort_t* __restrict__ A, const ushort_t* __restrict__ Wo,
    const float* __restrict__ bo, float* __restrict__ out)
{
    __shared__ __align__(16) ushort_t Sh[2][128][72];   // As=Sh[0], Bs=Sh[1]

    const int tid  = threadIdx.x;
    const int lane = tid & 63;
    const int w    = tid >> 6;          // wave: rows [32w, 32w+32)
    const int m    = lane & 15;
    const int qd   = lane >> 4;

    const int lin  = blockIdx.x;        // 0..255
    const int xcd  = lin & 7;
    const int slot = lin >> 3;          // 0..31
    const int n0   = (xcd * 4 + (slot & 3)) * 128;
    const int o0   = (slot >> 2) * 128;

    const int srow = tid >> 3;          // staging rows: srow, srow+32, +64, +96
    const int ssub = tid & 7;

    uint4 pa[4], pb[4];
#pragma unroll
    for (int l = 0; l < 4; l++) {
        pa[l] = *(const uint4*)&A[(size_t)(n0 + srow + 32 * l) * 1024 + ssub * 8];
        pb[l] = *(const uint4*)&Wo[(size_t)(o0 + srow + 32 * l) * 1024 + ssub * 8];
    }

    f32x4 acc[2][8];
#pragma unroll
    for (int rt = 0; rt < 2; rt++)
#pragma unroll
        for (int ct = 0; ct < 8; ct++) acc[rt][ct] = {0.f, 0.f, 0.f, 0.f};

    for (int k0 = 0; k0 < 1024; k0 += 64) {
        __syncthreads();                // previous compute done reading LDS
#pragma unroll
        for (int l = 0; l < 4; l++) {
            *(uint4*)&Sh[0][srow + 32 * l][ssub * 8] = pa[l];
            *(uint4*)&Sh[1][srow + 32 * l][ssub * 8] = pb[l];
        }
        __syncthreads();

        if (k0 + 64 < 1024) {           // issue next tile's loads early
            const int kn = k0 + 64;
#pragma unroll
            for (int l = 0; l < 4; l++) {
                pa[l] = *(const uint4*)&A[(size_t)(n0 + srow + 32 * l) * 1024 + kn + ssub * 8];
                pb[l] = *(const uint4*)&Wo[(size_t)(o0 + srow + 32 * l) * 1024 + kn + ssub * 8];
            }
        }

#pragma unroll
        for (int ks = 0; ks < 2; ks++) {
            bf16x8 af[2];
#pragma unroll
            for (int rt = 0; rt < 2; rt++)
                af[rt] = *(const bf16x8*)&Sh[0][32 * w + rt * 16 + m][ks * 32 + qd * 8];
#pragma unroll
            for (int ct = 0; ct < 8; ct++) {
                bf16x8 bf = *(const bf16x8*)&Sh[1][ct * 16 + m][ks * 32 + qd * 8];
#pragma unroll
                for (int rt = 0; rt < 2; rt++)
                    acc[rt][ct] = __builtin_amdgcn_mfma_f32_16x16x32_bf16(
                        af[rt], bf, acc[rt][ct], 0, 0, 0);
            }
        }
    }

    // bias per output column owned by this lane
    float bias[8];
#pragma unroll
    for (int ct = 0; ct < 8; ct++) bias[ct] = bo[o0 + ct * 16 + m];

    // ---- LDS-staged epilogue: two 64-row halves, coalesced float4 stores ----
    float* Cs = (float*)&Sh[0][0][0];   // 64 x 132 fp32 = 33792 B (fits 36864)
#pragma unroll
    for (int h = 0; h < 2; h++) {
        __syncthreads();                // protect prior LDS reads
        if ((w >> 1) == h) {
            const int lr0 = 32 * (w & 1);
#pragma unroll
            for (int rt = 0; rt < 2; rt++)
#pragma unroll
                for (int reg = 0; reg < 4; reg++) {
                    const int lr = lr0 + rt * 16 + qd * 4 + reg;
#pragma unroll
                    for (int ct = 0; ct < 8; ct++)
                        Cs[lr * 132 + ct * 16 + m] = acc[rt][ct][reg] + bias[ct];
                }
        }
        __syncthreads();
#pragma unroll
        for (int l = 0; l < 8; l++) {
            const int idx = tid + 256 * l;      // < 2048
            const int lr  = idx >> 5;           // 0..63
            const int c4  = idx & 31;           // float4 index within row
            const float4 val = *(const float4*)&Cs[lr * 132 + c4 * 4];
            *(float4*)&out[(size_t)(n0 + 64 * h + lr) * 1024 + o0 + c4 * 4] = val;
        }
    }
}

// ---------------------------------------------------------------------------
// Launcher.  ws (ushort): q16|k16|v16 (4M each) | er16 (1M) | wo16 (1M)
//            | M16 (4M) | vmean f32 (4096)
// Launches: memset + 3 kernels (cvt folded into prep).
// ---------------------------------------------------------------------------
extern "C" void kernel_launch(void* const* d_in, const int* in_sizes, int n_in,
                              void* d_out, int out_size, void* d_ws, size_t ws_size,
                              hipStream_t stream)
{
    const float* x    = (const float*)d_in[0];
    const int*   mask = (const int*)d_in[1];
    const float* Wq   = (const float*)d_in[2];
    const float* Wk   = (const float*)d_in[3];
    const float* Wv   = (const float*)d_in[4];
    const float* Er   = (const float*)d_in[5];
    const float* Wo   = (const float*)d_in[6];
    const float* bo   = (const float*)d_in[7];
    float* out = (float*)d_out;

    const size_t QKV = (size_t)BB * HH * TT * SS;
    const int    nEr = HH * TT * SS;
    const int    nWo = EE * EE;
    ushort_t* q16   = (ushort_t*)d_ws;
    ushort_t* k16   = q16 + QKV;
    ushort_t* v16   = k16 + QKV;
    ushort_t* er16  = v16 + QKV;
    ushort_t* wo16  = er16 + nEr;
    ushort_t* M16   = wo16 + nWo;
    float*    vmean = (float*)(M16 + QKV);

    hipMemsetAsync(vmean, 0, BB * HH * SS * sizeof(float), stream);
    prep_kernel<<<dim3(2048 + 512), 256, 0, stream>>>(
        Er, er16, Wo, wo16, x, Wq, Wk, Wv, q16, k16, v16, vmean);
    attn_kernel<<<dim3(BB * HH, TT / 64), 256, 0, stream>>>(q16, k16, v16, er16, mask, vmean, M16);
    outproj_kernel<<<dim3(256), 256, 0, stream>>>(M16, wo16, bo, out);
}